// Round 1
// baseline (17.443 us; speedup 1.0000x reference)
//
#include <hip/hip_runtime.h>
#include <math.h>

// Problem shape (fixed by setup_inputs): B=512, M=256, K=2.
// Only the diagonal of the (B,B) kernel matrix survives, so we compute
// per-i sums directly: out = (1/(B*K*M)) * sum_{i,k,m} exp(logp[i,i,k,m]).
#define PB 512
#define PM 256
#define PK 2

// inv_sqrt(2*pi) / (B * K * M)  -- folds the 1/sqrt(2pi) factor and both means
__device__ __constant__ float SCALE = 0.3989422804014327f / (512.0f * 512.0f);

__global__ __launch_bounds__(256)
void positive_prob_kernel(const float* __restrict__ z1,
                          const float* __restrict__ z2,
                          float* __restrict__ out) {
    const int i = blockIdx.x;   // sample index (diagonal element)
    const int m = threadIdx.x;  // feature index

    // z1 row i: first M entries are means, next M are log-variances
    const float mean = z1[i * (2 * PM) + m];
    const float lv   = z1[i * (2 * PM) + PM + m];
    const float inv_std = __expf(-0.5f * lv);   // 1/std = exp(-0.5*lv)

    float acc = 0.0f;
    #pragma unroll
    for (int k = 0; k < PK; ++k) {
        // z2r[i,k,m] = z2[k*B + i, m]
        const float x = z2[(k * PB + i) * PM + m];
        const float d = (x - mean) * inv_std;
        acc += __expf(-0.5f * d * d);
    }
    // exp(logp) = exp(-0.5*d^2) * inv_std / sqrt(2*pi); fold inv_std here,
    // 1/sqrt(2pi) and the means are folded into SCALE.
    acc *= inv_std;

    // Wave (64-lane) reduction
    #pragma unroll
    for (int off = 32; off > 0; off >>= 1)
        acc += __shfl_down(acc, off, 64);

    // Cross-wave reduction (4 waves per block)
    __shared__ float partial[4];
    const int wave = threadIdx.x >> 6;
    const int lane = threadIdx.x & 63;
    if (lane == 0) partial[wave] = acc;
    __syncthreads();

    if (threadIdx.x == 0) {
        float s = partial[0] + partial[1] + partial[2] + partial[3];
        atomicAdd(out, s * SCALE);
    }
}

extern "C" void kernel_launch(void* const* d_in, const int* in_sizes, int n_in,
                              void* d_out, int out_size, void* d_ws, size_t ws_size,
                              hipStream_t stream) {
    const float* z1 = (const float*)d_in[0];  // (512, 512) fp32
    const float* z2 = (const float*)d_in[1];  // (1024, 256) fp32
    float* out = (float*)d_out;               // 1 fp32 scalar

    // d_out is poisoned (0xAA) before timing and never re-poisoned; zero it
    // every call so the atomicAdd accumulation is correct and deterministic
    // across replays. hipMemsetAsync is graph-capture safe.
    hipMemsetAsync(out, 0, sizeof(float), stream);

    positive_prob_kernel<<<PB, 256, 0, stream>>>(z1, z2, out);
}

// Round 2
// 11.191 us; speedup vs baseline: 1.5587x; 1.5587x over previous
//
#include <hip/hip_runtime.h>
#include <math.h>

// Problem shape (fixed by setup_inputs): B=512, M=256, K=2.
// Only the diagonal of the (B,B) kernel matrix survives:
//   out = (1/(B*K*M)) * sum_{i,k,m} exp(-0.5*d^2) * inv_std[i,m] / sqrt(2pi)
//   d = (z2[k*B+i,m] - z1[i,m]) * inv_std[i,m],  inv_std = exp(-0.5*z1[i,M+m])
#define PB 512
#define PM 256
#define PK 2

#define GRID1 128              // partial-sum blocks
#define I_PER_BLK (PB / GRID1) // 4 sample rows per block

// inv_sqrt(2*pi) / (B*K*M)
#define SCALE (0.3989422804014327f / (512.0f * 512.0f))

// Stage 1: each block accumulates 4 sample rows, writes ONE partial to ws.
// Plain store (overwrite) -> no initialization of ws needed, no atomics.
__global__ __launch_bounds__(256)
void pp_partial(const float* __restrict__ z1,
                const float* __restrict__ z2,
                float* __restrict__ ws) {
    const int m = threadIdx.x;  // feature index, coalesced across lanes

    float acc = 0.0f;
    #pragma unroll
    for (int ii = 0; ii < I_PER_BLK; ++ii) {
        const int i = blockIdx.x * I_PER_BLK + ii;
        const float mean = z1[i * (2 * PM) + m];
        const float lv   = z1[i * (2 * PM) + PM + m];
        const float inv_std = __expf(-0.5f * lv);   // 1/std

        const float x0 = z2[(0 * PB + i) * PM + m];
        const float x1 = z2[(1 * PB + i) * PM + m];
        const float d0 = (x0 - mean) * inv_std;
        const float d1 = (x1 - mean) * inv_std;
        acc += (__expf(-0.5f * d0 * d0) + __expf(-0.5f * d1 * d1)) * inv_std;
    }

    // Wave (64-lane) reduction
    #pragma unroll
    for (int off = 32; off > 0; off >>= 1)
        acc += __shfl_down(acc, off, 64);

    // Cross-wave reduction (4 waves per block)
    __shared__ float partial[4];
    const int wave = threadIdx.x >> 6;
    const int lane = threadIdx.x & 63;
    if (lane == 0) partial[wave] = acc;
    __syncthreads();

    if (threadIdx.x == 0)
        ws[blockIdx.x] = partial[0] + partial[1] + partial[2] + partial[3];
}

// Stage 2: one wave reduces the 128 partials, writes the scalar output.
__global__ __launch_bounds__(64)
void pp_final(const float* __restrict__ ws, float* __restrict__ out) {
    const int lane = threadIdx.x;
    float v = ws[lane] + ws[lane + 64];
    #pragma unroll
    for (int off = 32; off > 0; off >>= 1)
        v += __shfl_down(v, off, 64);
    if (lane == 0) out[0] = v * SCALE;
}

extern "C" void kernel_launch(void* const* d_in, const int* in_sizes, int n_in,
                              void* d_out, int out_size, void* d_ws, size_t ws_size,
                              hipStream_t stream) {
    const float* z1 = (const float*)d_in[0];  // (512, 512) fp32
    const float* z2 = (const float*)d_in[1];  // (1024, 256) fp32
    float* out = (float*)d_out;               // 1 fp32 scalar
    float* ws  = (float*)d_ws;                // 128 fp32 partials

    pp_partial<<<GRID1, 256, 0, stream>>>(z1, z2, ws);
    pp_final<<<1, 64, 0, stream>>>(ws, out);
}